// Round 1
// baseline (1687.956 us; speedup 1.0000x reference)
//
#include <hip/hip_runtime.h>

#define EPSB 1e-5f

// problem sizes
#define B_   8
#define C_   512
#define T_   8
#define HW_  784
#define S_   6272     // T*HW
#define R_   64
#define CQ_  128
#define K_   4
#define P_   512      // T*R

// ---- workspace offsets (in floats) ----
#define O_TP    0u          // template_p      B*R*HW     = 401408
#define O_TR    401408u     // template_resample (B,R,C)  = 262144
#define O_FUSEK 663552u     // fuse per-k (B*K,CQ,P)      = 2097152
#define O_FUSE  2760704u    // fuse maxk  (B,CQ,P)        = 524288
#define O_TCT   3284992u    // tc transposed (B,P,C)      = 2097152
#define O_PTS   5382144u    // points (B,C,P)             = 2097152
#define O_M     7479296u    // softmax max (B,S)          = 50176
#define O_D     7529472u    // softmax 1/den (B,S)        = 50176
#define O_INDS  7579648u    // top4 inds (B,K,T,R) int    = 16384
#define O_L     7596032u    // logits, GB*P*S floats

// ============================================================
// K1: template_p[b,r,s] = bn1( sum_c w_reduce[r,c] * x[b,c,0,s] )
// grid 512 = B*R
__global__ __launch_bounds__(256) void k_template(
    const float* __restrict__ x, const float* __restrict__ wr_g,
    const float* __restrict__ g1, const float* __restrict__ b1,
    const float* __restrict__ m1, const float* __restrict__ v1,
    float* __restrict__ ws)
{
    __shared__ float wr[C_];
    int bid = blockIdx.x;
    int b = bid >> 6, r = bid & 63;
    int tid = threadIdx.x;
    wr[tid]       = wr_g[r*C_ + tid];
    wr[tid + 256] = wr_g[r*C_ + tid + 256];
    __syncthreads();
    float sc = g1[r] * rsqrtf(v1[r] + EPSB);
    float sh = b1[r] - m1[r]*sc;
    const float* xp = x + (size_t)b*C_*S_;
    for (int s = tid; s < HW_; s += 256) {
        float acc = 0.f;
        #pragma unroll 8
        for (int c = 0; c < C_; ++c) acc += wr[c] * xp[(size_t)c*S_ + s];
        ws[O_TP + (size_t)bid*HW_ + s] = acc*sc + sh;
    }
}

// ============================================================
// K2: argmax over s of template_p, then gather template_resample[b,r,c]=x[b,c,0,ind]
// grid 512 = B*R
__global__ __launch_bounds__(256) void k_argmax_gather(
    const float* __restrict__ x, float* __restrict__ ws)
{
    __shared__ float sval[256];
    __shared__ int   sidx[256];
    int bid = blockIdx.x;
    int b = bid >> 6;
    int tid = threadIdx.x;
    const float* tp = ws + O_TP + (size_t)bid*HW_;
    float best = -INFINITY; int bi = 0;
    for (int s = tid; s < HW_; s += 256) {
        float v = tp[s];
        if (v > best) { best = v; bi = s; }   // keeps lowest s within thread
    }
    sval[tid] = best; sidx[tid] = bi;
    __syncthreads();
    for (int off = 128; off > 0; off >>= 1) {
        if (tid < off) {
            float ov = sval[tid+off]; int oi = sidx[tid+off];
            if (ov > sval[tid] || (ov == sval[tid] && oi < sidx[tid])) {
                sval[tid] = ov; sidx[tid] = oi;
            }
        }
        __syncthreads();
    }
    int ind = sidx[0];
    for (int c = tid; c < C_; c += 256)
        ws[O_TR + (size_t)bid*C_ + c] = x[(size_t)(b*C_ + c)*S_ + ind];
}

// ============================================================
// K3: affinity[b,r,t,s] = sum_c tr[b,r,c]*x[b,c,t,s]; per (b,r,t) top-4 inds
// grid 512 = B*T*8 (8 r's per block)
__global__ __launch_bounds__(256) void k_afftop(
    const float* __restrict__ x, const float* __restrict__ ws, int* __restrict__ inds)
{
    __shared__ float trr[8][C_];     // 16 KB
    __shared__ float aff[8][HW_];    // 25 KB
    __shared__ float sval[256];
    __shared__ int   sidx[256];
    int bid = blockIdx.x;
    int b = bid >> 6, t = (bid >> 3) & 7, rg = bid & 7;
    int tid = threadIdx.x;
    for (int li = tid; li < 8*C_; li += 256) {
        int j = li >> 9, c = li & 511;
        trr[j][c] = ws[O_TR + (size_t)(b*R_ + rg*8 + j)*C_ + c];
    }
    __syncthreads();
    const float* xp = x + (size_t)b*C_*S_ + t*HW_;
    for (int s = tid; s < HW_; s += 256) {
        float a[8] = {0,0,0,0,0,0,0,0};
        for (int c = 0; c < C_; ++c) {
            float xv = xp[(size_t)c*S_ + s];
            #pragma unroll
            for (int j = 0; j < 8; ++j) a[j] += trr[j][c]*xv;
        }
        #pragma unroll
        for (int j = 0; j < 8; ++j) aff[j][s] = a[j];
    }
    __syncthreads();
    for (int j = 0; j < 8; ++j) {
        for (int pass = 0; pass < 4; ++pass) {
            float best = -INFINITY; int bi = 0;
            for (int s = tid; s < HW_; s += 256) {
                float v = aff[j][s];
                if (v > best) { best = v; bi = s; }
            }
            sval[tid] = best; sidx[tid] = bi;
            __syncthreads();
            for (int off = 128; off > 0; off >>= 1) {
                if (tid < off) {
                    float ov = sval[tid+off]; int oi = sidx[tid+off];
                    if (ov > sval[tid] || (ov == sval[tid] && oi < sidx[tid])) {
                        sval[tid] = ov; sidx[tid] = oi;
                    }
                }
                __syncthreads();
            }
            if (tid == 0) {
                inds[((b*K_ + pass)*T_ + t)*R_ + rg*8 + j] = sidx[0];
                aff[j][sidx[0]] = -INFINITY;
            }
            __syncthreads();
        }
    }
}

// ============================================================
// K4: points[b,c,p] = mean_k x[b,c,t,ind[b,k,t,r]],  p = t*64+r
// grid 8192
__global__ __launch_bounds__(256) void k_points(
    const float* __restrict__ x, float* __restrict__ ws, const int* __restrict__ inds)
{
    int idx = blockIdx.x*256 + threadIdx.x;      // B*C*P = 2^21
    int p = idx & 511, c = (idx >> 9) & 511, b = idx >> 18;
    int t = p >> 6, r = p & 63;
    const float* xp = x + (size_t)(b*C_ + c)*S_ + t*HW_;
    float s = 0.f;
    #pragma unroll
    for (int k = 0; k < K_; ++k)
        s += xp[inds[((b*K_ + k)*T_ + t)*R_ + r]];
    ws[O_PTS + (size_t)idx] = 0.25f*s;
}

// ============================================================
// K5: fuse_k[bk,q,t,r] = bn2( sum_c w_proj[q,c]*x[b,c,t,ind] + wrow*row + wcol*col )
// grid 256 = B*K*T
__global__ __launch_bounds__(256) void k_fuse(
    const float* __restrict__ x, const float* __restrict__ wp,
    const float* __restrict__ g2, const float* __restrict__ b2,
    const float* __restrict__ m2, const float* __restrict__ v2,
    float* __restrict__ ws, const int* __restrict__ inds)
{
    __shared__ float wps[64][132];   // [c_l][q], padded
    __shared__ float tile[64][64];   // [c_l][r]
    __shared__ int   indr[64];
    __shared__ float rowv[64], colv[64];
    int bid = blockIdx.x;
    int t = bid & 7, bk = bid >> 3;  // bk = b*4+k
    int b = bk >> 2;
    int tid = threadIdx.x;
    if (tid < 64) {
        int id = inds[bk*T_*R_ + t*R_ + tid];
        indr[tid] = id;
        rowv[tid] = (float)(id / 28) * (1.0f/28.0f);
        colv[tid] = (float)(id % 28) * (1.0f/28.0f);
    }
    __syncthreads();
    int qg = tid >> 4, rg = tid & 15;
    float acc[8][4] = {};
    for (int c0 = 0; c0 < C_; c0 += 64) {
        #pragma unroll
        for (int i = 0; i < 32; ++i) {
            int li = tid + i*256;
            int q = li >> 6, cl = li & 63;
            wps[cl][q] = wp[q*514 + c0 + cl];
        }
        #pragma unroll
        for (int i = 0; i < 16; ++i) {
            int li = tid + i*256;
            int cl = li >> 6, r = li & 63;
            tile[cl][r] = x[(size_t)(b*C_ + c0 + cl)*S_ + t*HW_ + indr[r]];
        }
        __syncthreads();
        #pragma unroll 4
        for (int cl = 0; cl < 64; ++cl) {
            float tv[4], wv[8];
            float4 t0 = *(const float4*)&tile[cl][rg*4];
            tv[0]=t0.x; tv[1]=t0.y; tv[2]=t0.z; tv[3]=t0.w;
            float4 w0 = *(const float4*)&wps[cl][qg*8];
            float4 w1 = *(const float4*)&wps[cl][qg*8+4];
            wv[0]=w0.x; wv[1]=w0.y; wv[2]=w0.z; wv[3]=w0.w;
            wv[4]=w1.x; wv[5]=w1.y; wv[6]=w1.z; wv[7]=w1.w;
            #pragma unroll
            for (int jq = 0; jq < 8; ++jq)
                #pragma unroll
                for (int jr = 0; jr < 4; ++jr)
                    acc[jq][jr] += wv[jq]*tv[jr];
        }
        __syncthreads();
    }
    #pragma unroll
    for (int jq = 0; jq < 8; ++jq) {
        int q = qg*8 + jq;
        float wrow = wp[q*514 + 512], wcol = wp[q*514 + 513];
        float sc = g2[q] * rsqrtf(v2[q] + EPSB);
        float sh = b2[q] - m2[q]*sc;
        #pragma unroll
        for (int jr = 0; jr < 4; ++jr) {
            int r = rg*4 + jr;
            float v = acc[jq][jr] + wrow*rowv[r] + wcol*colv[r];
            ws[O_FUSEK + (size_t)(bk*CQ_ + q)*P_ + t*R_ + r] = v*sc + sh;
        }
    }
}

// ============================================================
// K6: fuse[b,q,p] = max_k fuse_k ; grid 2048
__global__ __launch_bounds__(256) void k_maxk(float* __restrict__ ws)
{
    int idx = blockIdx.x*256 + threadIdx.x;   // B*CQ*P = 2^19
    int b = idx >> 16;
    int qp = idx & 65535;
    size_t base = O_FUSEK + (size_t)(b*4)*CQ_*P_ + qp;
    float m = ws[base];
    #pragma unroll
    for (int k = 1; k < K_; ++k) m = fmaxf(m, ws[base + (size_t)k*CQ_*P_]);
    ws[O_FUSE + (size_t)idx] = m;
}

// ============================================================
// K7: temporal conv (3 tap over t) + bn3 + relu, writes tc TRANSPOSED (B,P,C)
// grid 256 = B * 4(co blocks of 128) * T
__global__ __launch_bounds__(256) void k_conv(
    const float* __restrict__ wt,
    const float* __restrict__ g3, const float* __restrict__ b3,
    const float* __restrict__ m3, const float* __restrict__ v3,
    float* __restrict__ ws)
{
    __shared__ float fs[64][64];     // [ci][r]
    __shared__ float wts[128][65];   // [co_l][ci], padded
    int bid = blockIdx.x;
    int t = bid & 7, cb = (bid >> 3) & 3, b = bid >> 5;
    int tid = threadIdx.x;
    int cog = tid >> 4, rg = tid & 15;
    float acc[8][4] = {};
    for (int dt = 0; dt < 3; ++dt) {
        int tt = t + dt - 1;
        if (tt < 0 || tt >= T_) continue;     // block-uniform
        for (int cih = 0; cih < 2; ++cih) {
            __syncthreads();
            #pragma unroll
            for (int i = 0; i < 16; ++i) {
                int li = tid + i*256;
                int ci = li >> 6, r = li & 63;
                fs[ci][r] = ws[O_FUSE + (size_t)(b*CQ_ + cih*64 + ci)*P_ + tt*R_ + r];
            }
            #pragma unroll
            for (int i = 0; i < 32; ++i) {
                int li = tid + i*256;
                int col = li >> 6, ci = li & 63;
                wts[col][ci] = wt[(size_t)((cb*128 + col)*CQ_ + cih*64 + ci)*3 + dt];
            }
            __syncthreads();
            #pragma unroll 4
            for (int ci = 0; ci < 64; ++ci) {
                float fv[4];
                float4 f0 = *(const float4*)&fs[ci][rg*4];
                fv[0]=f0.x; fv[1]=f0.y; fv[2]=f0.z; fv[3]=f0.w;
                #pragma unroll
                for (int jq = 0; jq < 8; ++jq) {
                    float w = wts[cog + 16*jq][ci];
                    #pragma unroll
                    for (int jr = 0; jr < 4; ++jr) acc[jq][jr] += w*fv[jr];
                }
            }
        }
    }
    #pragma unroll
    for (int jq = 0; jq < 8; ++jq) {
        int co = cb*128 + cog + 16*jq;
        float sc = g3[co] * rsqrtf(v3[co] + EPSB);
        float sh = b3[co] - m3[co]*sc;
        #pragma unroll
        for (int jr = 0; jr < 4; ++jr) {
            int r = rg*4 + jr;
            float v = acc[jq][jr]*sc + sh;
            ws[O_TCT + (size_t)(b*P_ + t*R_ + r)*C_ + co] = fmaxf(v, 0.f);
        }
    }
}

// ============================================================
// K8: L[p,s] = sum_c points[b,c,p]*x[b,c,s]   (per local-b slice of L)
// grid (49, 4, GB)
__global__ __launch_bounds__(256) void k_gemmL(
    const float* __restrict__ x, float* __restrict__ ws, int bstart)
{
    __shared__ float As[32][128];  // [c][p]
    __shared__ float Bs[32][128];  // [c][s]
    int bl = blockIdx.z; int b = bstart + bl;
    int s0 = blockIdx.x*128, p0 = blockIdx.y*128;
    int tid = threadIdx.x;
    int tx = tid & 15, ty = tid >> 4;
    const float* A  = ws + O_PTS + (size_t)b*C_*P_;
    const float* Bx = x + (size_t)b*C_*S_;
    float* L = ws + O_L + (size_t)bl*P_*S_;
    float acc[8][8] = {};
    for (int c0 = 0; c0 < C_; c0 += 32) {
        #pragma unroll
        for (int i = 0; i < 4; ++i) {
            int li = tid + i*256;
            int cl = li >> 5, q4 = li & 31;
            *(float4*)&As[cl][q4*4] = *(const float4*)&A[(size_t)(c0+cl)*P_ + p0 + q4*4];
            *(float4*)&Bs[cl][q4*4] = *(const float4*)&Bx[(size_t)(c0+cl)*S_ + s0 + q4*4];
        }
        __syncthreads();
        #pragma unroll 8
        for (int cl = 0; cl < 32; ++cl) {
            float av[8], bv[8];
            float4 a0 = *(const float4*)&As[cl][ty*8];
            float4 a1 = *(const float4*)&As[cl][ty*8+4];
            float4 v0 = *(const float4*)&Bs[cl][tx*8];
            float4 v1 = *(const float4*)&Bs[cl][tx*8+4];
            av[0]=a0.x; av[1]=a0.y; av[2]=a0.z; av[3]=a0.w;
            av[4]=a1.x; av[5]=a1.y; av[6]=a1.z; av[7]=a1.w;
            bv[0]=v0.x; bv[1]=v0.y; bv[2]=v0.z; bv[3]=v0.w;
            bv[4]=v1.x; bv[5]=v1.y; bv[6]=v1.z; bv[7]=v1.w;
            #pragma unroll
            for (int i = 0; i < 8; ++i)
                #pragma unroll
                for (int j = 0; j < 8; ++j)
                    acc[i][j] += av[i]*bv[j];
        }
        __syncthreads();
    }
    #pragma unroll
    for (int i = 0; i < 8; ++i) {
        float* Lp = L + (size_t)(p0 + ty*8 + i)*S_ + s0 + tx*8;
        float4 o0, o1;
        o0.x=acc[i][0]; o0.y=acc[i][1]; o0.z=acc[i][2]; o0.w=acc[i][3];
        o1.x=acc[i][4]; o1.y=acc[i][5]; o1.z=acc[i][6]; o1.w=acc[i][7];
        *(float4*)&Lp[0] = o0;
        *(float4*)&Lp[4] = o1;
    }
}

// ============================================================
// K9: per-(b,s) softmax stats over p: M = max, D = 1/sum(exp(L-M))
// grid (25, GB)
__global__ __launch_bounds__(256) void k_softmax(float* __restrict__ ws, int bstart)
{
    int s = blockIdx.x*256 + threadIdx.x;
    if (s >= S_) return;
    int bl = blockIdx.y; int b = bstart + bl;
    const float* L = ws + O_L + (size_t)bl*P_*S_ + s;
    float m = -INFINITY;
    for (int p = 0; p < P_; ++p) m = fmaxf(m, L[(size_t)p*S_]);
    float sum = 0.f;
    for (int p = 0; p < P_; ++p) sum += __expf(L[(size_t)p*S_] - m);
    ws[O_M + (size_t)b*S_ + s] = m;
    ws[O_D + (size_t)b*S_ + s] = 1.0f/sum;
}

// ============================================================
// K10: out[c,s] = x[c,s] + invD[s] * sum_p tcT[p,c]*exp(L[p,s]-M[s])
// grid (49, 4, GB)
__global__ __launch_bounds__(256) void k_gemmP(
    const float* __restrict__ x, float* __restrict__ ws,
    float* __restrict__ out, int bstart)
{
    __shared__ float As[32][128];  // [p][c]  (tcT)
    __shared__ float Es[32][128];  // [p][s]  (exp(L-M))
    __shared__ float Ms[128], Ds[128];
    int bl = blockIdx.z; int b = bstart + bl;
    int s0 = blockIdx.x*128, c0 = blockIdx.y*128;
    int tid = threadIdx.x;
    int tx = tid & 15, ty = tid >> 4;
    const float* A = ws + O_TCT + (size_t)b*P_*C_;
    const float* L = ws + O_L + (size_t)bl*P_*S_;
    if (tid < 128) Ms[tid]      = ws[O_M + (size_t)b*S_ + s0 + tid];
    else           Ds[tid-128]  = ws[O_D + (size_t)b*S_ + s0 + tid - 128];
    __syncthreads();
    float acc[8][8] = {};
    for (int p0 = 0; p0 < P_; p0 += 32) {
        #pragma unroll
        for (int i = 0; i < 4; ++i) {
            int li = tid + i*256;
            int pl = li >> 5, q4 = li & 31;
            *(float4*)&As[pl][q4*4] = *(const float4*)&A[(size_t)(p0+pl)*C_ + c0 + q4*4];
            float4 lv = *(const float4*)&L[(size_t)(p0+pl)*S_ + s0 + q4*4];
            float4 ev;
            ev.x = __expf(lv.x - Ms[q4*4+0]);
            ev.y = __expf(lv.y - Ms[q4*4+1]);
            ev.z = __expf(lv.z - Ms[q4*4+2]);
            ev.w = __expf(lv.w - Ms[q4*4+3]);
            *(float4*)&Es[pl][q4*4] = ev;
        }
        __syncthreads();
        #pragma unroll 8
        for (int pl = 0; pl < 32; ++pl) {
            float av[8], bv[8];
            float4 a0 = *(const float4*)&As[pl][ty*8];
            float4 a1 = *(const float4*)&As[pl][ty*8+4];
            float4 v0 = *(const float4*)&Es[pl][tx*8];
            float4 v1 = *(const float4*)&Es[pl][tx*8+4];
            av[0]=a0.x; av[1]=a0.y; av[2]=a0.z; av[3]=a0.w;
            av[4]=a1.x; av[5]=a1.y; av[6]=a1.z; av[7]=a1.w;
            bv[0]=v0.x; bv[1]=v0.y; bv[2]=v0.z; bv[3]=v0.w;
            bv[4]=v1.x; bv[5]=v1.y; bv[6]=v1.z; bv[7]=v1.w;
            #pragma unroll
            for (int i = 0; i < 8; ++i)
                #pragma unroll
                for (int j = 0; j < 8; ++j)
                    acc[i][j] += av[i]*bv[j];
        }
        __syncthreads();
    }
    #pragma unroll
    for (int i = 0; i < 8; ++i) {
        int c = c0 + ty*8 + i;
        size_t oidx = (size_t)(b*C_ + c)*S_ + s0 + tx*8;
        #pragma unroll
        for (int j4 = 0; j4 < 2; ++j4) {
            float4 xv = *(const float4*)&x[oidx + j4*4];
            float4 o;
            o.x = xv.x + acc[i][j4*4+0]*Ds[tx*8+j4*4+0];
            o.y = xv.y + acc[i][j4*4+1]*Ds[tx*8+j4*4+1];
            o.z = xv.z + acc[i][j4*4+2]*Ds[tx*8+j4*4+2];
            o.w = xv.w + acc[i][j4*4+3]*Ds[tx*8+j4*4+3];
            *(float4*)&out[oidx + j4*4] = o;
        }
    }
}

// ============================================================
extern "C" void kernel_launch(void* const* d_in, const int* in_sizes, int n_in,
                              void* d_out, int out_size, void* d_ws, size_t ws_size,
                              hipStream_t stream) {
    const float* x   = (const float*)d_in[0];
    const float* wrd = (const float*)d_in[1];
    const float* g1  = (const float*)d_in[2];
    const float* b1  = (const float*)d_in[3];
    const float* m1  = (const float*)d_in[4];
    const float* v1  = (const float*)d_in[5];
    const float* wp  = (const float*)d_in[6];
    const float* g2  = (const float*)d_in[7];
    const float* b2  = (const float*)d_in[8];
    const float* m2  = (const float*)d_in[9];
    const float* v2  = (const float*)d_in[10];
    const float* wt  = (const float*)d_in[11];
    const float* g3  = (const float*)d_in[12];
    const float* b3  = (const float*)d_in[13];
    const float* m3  = (const float*)d_in[14];
    const float* v3  = (const float*)d_in[15];
    float* ws  = (float*)d_ws;
    float* out = (float*)d_out;
    int*   inds = (int*)(ws + O_INDS);

    k_template<<<512, 256, 0, stream>>>(x, wrd, g1, b1, m1, v1, ws);
    k_argmax_gather<<<512, 256, 0, stream>>>(x, ws);
    k_afftop<<<512, 256, 0, stream>>>(x, ws, inds);
    k_points<<<8192, 256, 0, stream>>>(x, ws, inds);
    k_fuse<<<256, 256, 0, stream>>>(x, wp, g2, b2, m2, v2, ws, inds);
    k_maxk<<<2048, 256, 0, stream>>>(ws);
    k_conv<<<256, 256, 0, stream>>>(wt, g3, b3, m3, v3, ws);

    // batch-group size for logit buffer, chosen deterministically from ws_size
    int GB = 1;
    if      (ws_size >= (O_L + 8ull*(size_t)P_*S_)*4ull) GB = 8;
    else if (ws_size >= (O_L + 4ull*(size_t)P_*S_)*4ull) GB = 4;
    else if (ws_size >= (O_L + 2ull*(size_t)P_*S_)*4ull) GB = 2;

    for (int g = 0; g < B_/GB; ++g) {
        int bs = g*GB;
        k_gemmL<<<dim3(49, 4, GB), 256, 0, stream>>>(x, ws, bs);
        k_softmax<<<dim3(25, GB), 256, 0, stream>>>(ws, bs);
        k_gemmP<<<dim3(49, 4, GB), 256, 0, stream>>>(x, ws, out, bs);
    }
}

// Round 2
// 1027.203 us; speedup vs baseline: 1.6433x; 1.6433x over previous
//
#include <hip/hip_runtime.h>

#define EPSB 1e-5f

// problem sizes
#define B_   8
#define C_   512
#define T_   8
#define HW_  784
#define S_   6272     // T*HW
#define R_   64
#define CQ_  128
#define K_   4
#define P_   512      // T*R

typedef _Float16 f16;
typedef __attribute__((ext_vector_type(8))) _Float16 f16x8;
typedef __attribute__((ext_vector_type(4))) _Float16 f16x4;
typedef __attribute__((ext_vector_type(4))) float    f32x4;

// ---- workspace byte offsets ----
// persistent region
#define OB_PTST  0ull                       // f16 [8][512][512]   4,194,304
#define OB_TC    4194304ull                 // f16 [8][512][512]   4,194,304
#define OB_D     8388608ull                 // f32 [8][6272]         200,704
#define OB_XT    8589312ull                 // f16 [8][6272][512] 51,380,224
#define OB_SH    59969536ull                // shared region start
// transients (all dead before gemmL) — overlap with LT/W region
#define T_TP     (OB_SH)                    // f32 [8*64][784]     1,605,632
#define T_TR     (OB_SH + 1605632ull)       // f32 [8*64][512]     1,048,576
#define T_INDS   (OB_SH + 2654208ull)       // int [8][4][8][64]      65,536
#define T_FUSEK  (OB_SH + 2719744ull)       // f16 [32][128][512]  4,194,304
#define T_FUSE   (OB_SH + 6914048ull)       // f32 [8][128][512]   2,097,152
// group arrays (start at OB_SH, used only after transients die):
//   LT f32 [GB][6272][512]  GB*12,845,056 ; W f16 [GB][6272][512] GB*6,422,528

__device__ __forceinline__ void gload16(const void* g, void* l) {
    __builtin_amdgcn_global_load_lds(
        (const __attribute__((address_space(1))) unsigned int*)g,
        (__attribute__((address_space(3))) unsigned int*)l, 16, 0, 0);
}

// ============================================================
// K0: transpose+convert x[b][c][s] f32 -> xT[b][s][c] f16
// grid (98, 8, 8) = (s-tile64, c-tile64, b)
__global__ __launch_bounds__(256) void k_xpose(
    const float* __restrict__ x, f16* __restrict__ xT)
{
    __shared__ float tile[64][65];
    int s0 = blockIdx.x*64, c0 = blockIdx.y*64, b = blockIdx.z;
    int tid = threadIdx.x;
    #pragma unroll
    for (int i = 0; i < 4; ++i) {
        int idx = tid + i*256;
        int cl = idx >> 4, s4 = (idx & 15)*4;
        f32x4 v = *(const f32x4*)&x[((size_t)(b*C_ + c0+cl))*S_ + s0 + s4];
        tile[cl][s4] = v.x; tile[cl][s4+1] = v.y;
        tile[cl][s4+2] = v.z; tile[cl][s4+3] = v.w;
    }
    __syncthreads();
    #pragma unroll
    for (int i = 0; i < 4; ++i) {
        int idx = tid + i*256;
        int sl = idx >> 4, c4 = (idx & 15)*4;
        f16x4 h;
        h[0] = (f16)tile[c4+0][sl]; h[1] = (f16)tile[c4+1][sl];
        h[2] = (f16)tile[c4+2][sl]; h[3] = (f16)tile[c4+3][sl];
        *(f16x4*)&xT[((size_t)(b*S_ + s0+sl))*C_ + c0 + c4] = h;
    }
}

// ============================================================
// K1: template_p[b,r,s] = bn1( sum_c w_reduce[r,c] * x[b,c,0,s] )
__global__ __launch_bounds__(256) void k_template(
    const float* __restrict__ x, const float* __restrict__ wr_g,
    const float* __restrict__ g1, const float* __restrict__ b1,
    const float* __restrict__ m1, const float* __restrict__ v1,
    float* __restrict__ tp)
{
    __shared__ float wr[C_];
    int bid = blockIdx.x;
    int b = bid >> 6, r = bid & 63;
    int tid = threadIdx.x;
    wr[tid]       = wr_g[r*C_ + tid];
    wr[tid + 256] = wr_g[r*C_ + tid + 256];
    __syncthreads();
    float sc = g1[r] * rsqrtf(v1[r] + EPSB);
    float sh = b1[r] - m1[r]*sc;
    const float* xp = x + (size_t)b*C_*S_;
    for (int s = tid; s < HW_; s += 256) {
        float acc = 0.f;
        #pragma unroll 8
        for (int c = 0; c < C_; ++c) acc += wr[c] * xp[(size_t)c*S_ + s];
        tp[(size_t)bid*HW_ + s] = acc*sc + sh;
    }
}

// ============================================================
// K2: argmax over s; gather template_resample[b,r,c] = x[b,c,0,ind]
__global__ __launch_bounds__(256) void k_argmax_gather(
    const float* __restrict__ x, const float* __restrict__ tp,
    float* __restrict__ tr)
{
    __shared__ float sval[256];
    __shared__ int   sidx[256];
    int bid = blockIdx.x;
    int b = bid >> 6;
    int tid = threadIdx.x;
    const float* row = tp + (size_t)bid*HW_;
    float best = -INFINITY; int bi = 0;
    for (int s = tid; s < HW_; s += 256) {
        float v = row[s];
        if (v > best) { best = v; bi = s; }
    }
    sval[tid] = best; sidx[tid] = bi;
    __syncthreads();
    for (int off = 128; off > 0; off >>= 1) {
        if (tid < off) {
            float ov = sval[tid+off]; int oi = sidx[tid+off];
            if (ov > sval[tid] || (ov == sval[tid] && oi < sidx[tid])) {
                sval[tid] = ov; sidx[tid] = oi;
            }
        }
        __syncthreads();
    }
    int ind = sidx[0];
    for (int c = tid; c < C_; c += 256)
        tr[(size_t)bid*C_ + c] = x[(size_t)(b*C_ + c)*S_ + ind];
}

// ============================================================
// K3: affinity + per (b,r,t) top-4 indices (fp32, round-1 verified)
__global__ __launch_bounds__(256) void k_afftop(
    const float* __restrict__ x, const float* __restrict__ tr,
    int* __restrict__ inds)
{
    __shared__ float trr[8][C_];
    __shared__ float aff[8][HW_];
    __shared__ float sval[256];
    __shared__ int   sidx[256];
    int bid = blockIdx.x;
    int b = bid >> 6, t = (bid >> 3) & 7, rg = bid & 7;
    int tid = threadIdx.x;
    for (int li = tid; li < 8*C_; li += 256) {
        int j = li >> 9, c = li & 511;
        trr[j][c] = tr[(size_t)(b*R_ + rg*8 + j)*C_ + c];
    }
    __syncthreads();
    const float* xp = x + (size_t)b*C_*S_ + t*HW_;
    for (int s = tid; s < HW_; s += 256) {
        float a[8] = {0,0,0,0,0,0,0,0};
        for (int c = 0; c < C_; ++c) {
            float xv = xp[(size_t)c*S_ + s];
            #pragma unroll
            for (int j = 0; j < 8; ++j) a[j] += trr[j][c]*xv;
        }
        #pragma unroll
        for (int j = 0; j < 8; ++j) aff[j][s] = a[j];
    }
    __syncthreads();
    for (int j = 0; j < 8; ++j) {
        for (int pass = 0; pass < 4; ++pass) {
            float best = -INFINITY; int bi = 0;
            for (int s = tid; s < HW_; s += 256) {
                float v = aff[j][s];
                if (v > best) { best = v; bi = s; }
            }
            sval[tid] = best; sidx[tid] = bi;
            __syncthreads();
            for (int off = 128; off > 0; off >>= 1) {
                if (tid < off) {
                    float ov = sval[tid+off]; int oi = sidx[tid+off];
                    if (ov > sval[tid] || (ov == sval[tid] && oi < sidx[tid])) {
                        sval[tid] = ov; sidx[tid] = oi;
                    }
                }
                __syncthreads();
            }
            if (tid == 0) {
                inds[((b*K_ + pass)*T_ + t)*R_ + rg*8 + j] = sidx[0];
                aff[j][sidx[0]] = -INFINITY;
            }
            __syncthreads();
        }
    }
}

// ============================================================
// K4: ptsT[b][p][c] f16 = mean_k x[b,c,t,ind[b,k,t,r]],  p=t*64+r
// grid (8 c-tiles, 8 t, 8 b)
__global__ __launch_bounds__(256) void k_pointsT(
    const float* __restrict__ x, const int* __restrict__ inds,
    f16* __restrict__ ptsT)
{
    __shared__ float tile[64][65];
    __shared__ int   indl[4][64];
    int c0 = blockIdx.x*64, t = blockIdx.y, b = blockIdx.z;
    int tid = threadIdx.x;
    {
        int k = tid >> 6, r = tid & 63;
        indl[k][r] = inds[((b*K_ + k)*T_ + t)*R_ + r];
    }
    __syncthreads();
    #pragma unroll
    for (int i = 0; i < 16; ++i) {
        int idx = tid + i*256;
        int cl = idx >> 6, r = idx & 63;
        const float* base = x + (size_t)(b*C_ + c0 + cl)*S_ + t*HW_;
        float v = base[indl[0][r]] + base[indl[1][r]] + base[indl[2][r]] + base[indl[3][r]];
        tile[cl][r] = 0.25f*v;
    }
    __syncthreads();
    #pragma unroll
    for (int i = 0; i < 16; ++i) {
        int idx = tid + i*256;
        int rl = idx >> 6, cl = idx & 63;
        ptsT[((size_t)b*P_ + t*64 + rl)*C_ + c0 + cl] = (f16)tile[cl][rl];
    }
}

// ============================================================
// K5: fuse_k (bn2 proj of gathered traj + coords), out f16
__global__ __launch_bounds__(256) void k_fuse(
    const float* __restrict__ x, const float* __restrict__ wp,
    const float* __restrict__ g2, const float* __restrict__ b2,
    const float* __restrict__ m2, const float* __restrict__ v2,
    f16* __restrict__ fusek, const int* __restrict__ inds)
{
    __shared__ float wps[64][132];
    __shared__ float tile[64][64];
    __shared__ int   indr[64];
    __shared__ float rowv[64], colv[64];
    int bid = blockIdx.x;
    int t = bid & 7, bk = bid >> 3;
    int b = bk >> 2;
    int tid = threadIdx.x;
    if (tid < 64) {
        int id = inds[bk*T_*R_ + t*R_ + tid];
        indr[tid] = id;
        rowv[tid] = (float)(id / 28) * (1.0f/28.0f);
        colv[tid] = (float)(id % 28) * (1.0f/28.0f);
    }
    __syncthreads();
    int qg = tid >> 4, rg = tid & 15;
    float acc[8][4] = {};
    for (int c0 = 0; c0 < C_; c0 += 64) {
        #pragma unroll
        for (int i = 0; i < 32; ++i) {
            int li = tid + i*256;
            int q = li >> 6, cl = li & 63;
            wps[cl][q] = wp[q*514 + c0 + cl];
        }
        #pragma unroll
        for (int i = 0; i < 16; ++i) {
            int li = tid + i*256;
            int cl = li >> 6, r = li & 63;
            tile[cl][r] = x[(size_t)(b*C_ + c0 + cl)*S_ + t*HW_ + indr[r]];
        }
        __syncthreads();
        #pragma unroll 4
        for (int cl = 0; cl < 64; ++cl) {
            float tv[4], wv[8];
            float4 t0 = *(const float4*)&tile[cl][rg*4];
            tv[0]=t0.x; tv[1]=t0.y; tv[2]=t0.z; tv[3]=t0.w;
            float4 w0 = *(const float4*)&wps[cl][qg*8];
            float4 w1 = *(const float4*)&wps[cl][qg*8+4];
            wv[0]=w0.x; wv[1]=w0.y; wv[2]=w0.z; wv[3]=w0.w;
            wv[4]=w1.x; wv[5]=w1.y; wv[6]=w1.z; wv[7]=w1.w;
            #pragma unroll
            for (int jq = 0; jq < 8; ++jq)
                #pragma unroll
                for (int jr = 0; jr < 4; ++jr)
                    acc[jq][jr] += wv[jq]*tv[jr];
        }
        __syncthreads();
    }
    #pragma unroll
    for (int jq = 0; jq < 8; ++jq) {
        int q = qg*8 + jq;
        float wrow = wp[q*514 + 512], wcol = wp[q*514 + 513];
        float sc = g2[q] * rsqrtf(v2[q] + EPSB);
        float sh = b2[q] - m2[q]*sc;
        #pragma unroll
        for (int jr = 0; jr < 4; ++jr) {
            int r = rg*4 + jr;
            float v = acc[jq][jr] + wrow*rowv[r] + wcol*colv[r];
            fusek[(size_t)(bk*CQ_ + q)*P_ + t*R_ + r] = (f16)(v*sc + sh);
        }
    }
}

// ============================================================
// K6: fuse[b,q,p] = max_k fuse_k (f16 in, f32 out)
__global__ __launch_bounds__(256) void k_maxk(
    const f16* __restrict__ fusek, float* __restrict__ fuse)
{
    int idx = blockIdx.x*256 + threadIdx.x;
    int b = idx >> 16;
    int qp = idx & 65535;
    const f16* base = fusek + (size_t)(b*4)*CQ_*P_ + qp;
    float m = (float)base[0];
    #pragma unroll
    for (int k = 1; k < K_; ++k) m = fmaxf(m, (float)base[(size_t)k*CQ_*P_]);
    fuse[(size_t)idx] = m;
}

// ============================================================
// K7: temporal conv + bn3 + relu -> tc f16 [b][c][p]
__global__ __launch_bounds__(256) void k_conv(
    const float* __restrict__ wt,
    const float* __restrict__ g3, const float* __restrict__ b3,
    const float* __restrict__ m3, const float* __restrict__ v3,
    const float* __restrict__ fuse, f16* __restrict__ tc)
{
    __shared__ float fs[64][64];
    __shared__ float wts[128][65];
    int bid = blockIdx.x;
    int t = bid & 7, cb = (bid >> 3) & 3, b = bid >> 5;
    int tid = threadIdx.x;
    int cog = tid >> 4, rg = tid & 15;
    float acc[8][4] = {};
    for (int dt = 0; dt < 3; ++dt) {
        int tt = t + dt - 1;
        if (tt < 0 || tt >= T_) continue;     // block-uniform
        for (int cih = 0; cih < 2; ++cih) {
            __syncthreads();
            #pragma unroll
            for (int i = 0; i < 16; ++i) {
                int li = tid + i*256;
                int ci = li >> 6, r = li & 63;
                fs[ci][r] = fuse[(size_t)(b*CQ_ + cih*64 + ci)*P_ + tt*R_ + r];
            }
            #pragma unroll
            for (int i = 0; i < 32; ++i) {
                int li = tid + i*256;
                int col = li >> 6, ci = li & 63;
                wts[col][ci] = wt[(size_t)((cb*128 + col)*CQ_ + cih*64 + ci)*3 + dt];
            }
            __syncthreads();
            #pragma unroll 4
            for (int ci = 0; ci < 64; ++ci) {
                float fv[4];
                float4 f0 = *(const float4*)&fs[ci][rg*4];
                fv[0]=f0.x; fv[1]=f0.y; fv[2]=f0.z; fv[3]=f0.w;
                #pragma unroll
                for (int jq = 0; jq < 8; ++jq) {
                    float w = wts[cog + 16*jq][ci];
                    #pragma unroll
                    for (int jr = 0; jr < 4; ++jr) acc[jq][jr] += w*fv[jr];
                }
            }
        }
    }
    #pragma unroll
    for (int jq = 0; jq < 8; ++jq) {
        int co = cb*128 + cog + 16*jq;
        float sc = g3[co] * rsqrtf(v3[co] + EPSB);
        float sh = b3[co] - m3[co]*sc;
        f16x4 h;
        #pragma unroll
        for (int jr = 0; jr < 4; ++jr)
            h[jr] = (f16)fmaxf(acc[jq][jr]*sc + sh, 0.f);
        *(f16x4*)&tc[((size_t)(b*C_ + co))*P_ + t*R_ + rg*4] = h;
    }
}

// ============================================================
// K8: LT[bl][s][p] = sum_c xT[b][s][c] * ptsT[b][p][c]   (f16 MFMA, fp32 out)
// grid (49, 4, gb) = (s-tile128, p-tile128, bl)
__global__ __launch_bounds__(256) void k_gemmL(
    const f16* __restrict__ xT, const f16* __restrict__ ptsT,
    float* __restrict__ LT, int bstart)
{
    __shared__ __align__(16) f16 As[128*32];
    __shared__ __align__(16) f16 Bs[128*32];
    int bl = blockIdx.z; int b = bstart + bl;
    int s0 = blockIdx.x*128, p0 = blockIdx.y*128;
    int tid = threadIdx.x;
    int lane = tid & 63, w = tid >> 6;
    int srow = w*16 + (lane >> 2);
    int scol = (lane & 3)*8;
    const f16* ga = xT   + ((size_t)b*S_ + s0 + srow)*C_ + scol;
    const f16* gb = ptsT + ((size_t)b*P_ + p0 + srow)*C_ + scol;
    float* Lg = LT + (size_t)bl*S_*P_;
    int mrow = (w & 1)*64, nrow = (w >> 1)*64;
    int fr = lane & 15, fk = (lane >> 4)*8, quad = lane >> 4;
    f32x4 acc[4][4] = {};
    for (int c0 = 0; c0 < C_; c0 += 32) {
        gload16(ga,           &As[w*512]);
        gload16(ga + 64*C_,   &As[2048 + w*512]);
        gload16(gb,           &Bs[w*512]);
        gload16(gb + 64*C_,   &Bs[2048 + w*512]);
        ga += 32; gb += 32;
        __syncthreads();
        f16x8 af[4], bf[4];
        #pragma unroll
        for (int mt = 0; mt < 4; ++mt)
            af[mt] = *(const f16x8*)&As[(mrow + mt*16 + fr)*32 + fk];
        #pragma unroll
        for (int nt = 0; nt < 4; ++nt)
            bf[nt] = *(const f16x8*)&Bs[(nrow + nt*16 + fr)*32 + fk];
        #pragma unroll
        for (int mt = 0; mt < 4; ++mt)
            #pragma unroll
            for (int nt = 0; nt < 4; ++nt)
                acc[mt][nt] = __builtin_amdgcn_mfma_f32_16x16x32_f16(
                    af[mt], bf[nt], acc[mt][nt], 0, 0, 0);
        __syncthreads();
    }
    #pragma unroll
    for (int mt = 0; mt < 4; ++mt) {
        int s = s0 + mrow + mt*16 + quad*4;
        #pragma unroll
        for (int nt = 0; nt < 4; ++nt) {
            int p = p0 + nrow + nt*16 + fr;
            #pragma unroll
            for (int i = 0; i < 4; ++i)
                Lg[(size_t)(s + i)*P_ + p] = acc[mt][nt][i];
        }
    }
}

// ============================================================
// K9: row softmax over p: W[bl][s][p] = f16(exp(L-m)), Dinv[b][s] = 1/sum
// grid (1568, gb); one wave per s-row
__global__ __launch_bounds__(256) void k_softmaxW(
    const float* __restrict__ LT, f16* __restrict__ W,
    float* __restrict__ Dinv, int bstart)
{
    int bl = blockIdx.y; int b = bstart + bl;
    int tid = threadIdx.x, w = tid >> 6, lane = tid & 63;
    int s = blockIdx.x*4 + w;
    const float* row = LT + ((size_t)bl*S_ + s)*P_ + lane*8;
    f32x4 v0 = *(const f32x4*)row;
    f32x4 v1 = *(const f32x4*)(row + 4);
    float m = fmaxf(fmaxf(fmaxf(v0.x, v0.y), fmaxf(v0.z, v0.w)),
                    fmaxf(fmaxf(v1.x, v1.y), fmaxf(v1.z, v1.w)));
    #pragma unroll
    for (int off = 1; off < 64; off <<= 1) m = fmaxf(m, __shfl_xor(m, off));
    float e[8];
    e[0] = __expf(v0.x - m); e[1] = __expf(v0.y - m);
    e[2] = __expf(v0.z - m); e[3] = __expf(v0.w - m);
    e[4] = __expf(v1.x - m); e[5] = __expf(v1.y - m);
    e[6] = __expf(v1.z - m); e[7] = __expf(v1.w - m);
    float sum = ((e[0]+e[1])+(e[2]+e[3])) + ((e[4]+e[5])+(e[6]+e[7]));
    #pragma unroll
    for (int off = 1; off < 64; off <<= 1) sum += __shfl_xor(sum, off);
    f16x8 h;
    #pragma unroll
    for (int j = 0; j < 8; ++j) h[j] = (f16)e[j];
    *(f16x8*)&W[((size_t)bl*S_ + s)*P_ + lane*8] = h;
    if (lane == 0) Dinv[(size_t)b*S_ + s] = 1.0f/sum;
}

// ============================================================
// K10: out[b][c][s] = x + Dinv[s] * sum_p tc[b][c][p] * W[bl][s][p]
// grid (49, 4, gb) = (s-tile128, c-tile128, bl)
__global__ __launch_bounds__(256) void k_gemmP(
    const f16* __restrict__ tc, const f16* __restrict__ W,
    const float* __restrict__ Dinv, const float* __restrict__ x,
    float* __restrict__ out, int bstart)
{
    __shared__ __align__(16) f16 As[128*32];
    __shared__ __align__(16) f16 Bs[128*32];
    int bl = blockIdx.z; int b = bstart + bl;
    int s0 = blockIdx.x*128, c0t = blockIdx.y*128;
    int tid = threadIdx.x;
    int lane = tid & 63, w = tid >> 6;
    int srow = w*16 + (lane >> 2);
    int scol = (lane & 3)*8;
    const f16* ga = tc + ((size_t)(b*C_) + c0t + srow)*P_ + scol;
    const f16* gb = W  + ((size_t)bl*S_ + s0 + srow)*P_ + scol;
    int mrow = (w & 1)*64, nrow = (w >> 1)*64;
    int fr = lane & 15, fk = (lane >> 4)*8, quad = lane >> 4;
    f32x4 acc[4][4] = {};
    for (int p0 = 0; p0 < P_; p0 += 32) {
        gload16(ga,           &As[w*512]);
        gload16(ga + 64*P_,   &As[2048 + w*512]);
        gload16(gb,           &Bs[w*512]);
        gload16(gb + 64*P_,   &Bs[2048 + w*512]);
        ga += 32; gb += 32;
        __syncthreads();
        f16x8 af[4], bf[4];
        #pragma unroll
        for (int mt = 0; mt < 4; ++mt)
            af[mt] = *(const f16x8*)&As[(mrow + mt*16 + fr)*32 + fk];
        #pragma unroll
        for (int nt = 0; nt < 4; ++nt)
            bf[nt] = *(const f16x8*)&Bs[(nrow + nt*16 + fr)*32 + fk];
        #pragma unroll
        for (int mt = 0; mt < 4; ++mt)
            #pragma unroll
            for (int nt = 0; nt < 4; ++nt)
                acc[mt][nt] = __builtin_amdgcn_mfma_f32_16x16x32_f16(
                    af[mt], bf[nt], acc[mt][nt], 0, 0, 0);
        __syncthreads();
    }
    #pragma unroll
    for (int nt = 0; nt < 4; ++nt) {
        int s = s0 + nrow + nt*16 + fr;
        float dv = Dinv[(size_t)b*S_ + s];
        #pragma unroll
        for (int mt = 0; mt < 4; ++mt) {
            int c = c0t + mrow + mt*16 + quad*4;
            #pragma unroll
            for (int i = 0; i < 4; ++i) {
                size_t o = ((size_t)(b*C_ + c + i))*S_ + s;
                out[o] = x[o] + acc[mt][nt][i]*dv;
            }
        }
    }
}

// ============================================================
extern "C" void kernel_launch(void* const* d_in, const int* in_sizes, int n_in,
                              void* d_out, int out_size, void* d_ws, size_t ws_size,
                              hipStream_t stream) {
    const float* x   = (const float*)d_in[0];
    const float* wrd = (const float*)d_in[1];
    const float* g1  = (const float*)d_in[2];
    const float* b1  = (const float*)d_in[3];
    const float* m1  = (const float*)d_in[4];
    const float* v1  = (const float*)d_in[5];
    const float* wp  = (const float*)d_in[6];
    const float* g2  = (const float*)d_in[7];
    const float* b2  = (const float*)d_in[8];
    const float* m2  = (const float*)d_in[9];
    const float* v2  = (const float*)d_in[10];
    const float* wt  = (const float*)d_in[11];
    const float* g3  = (const float*)d_in[12];
    const float* b3  = (const float*)d_in[13];
    const float* m3  = (const float*)d_in[14];
    const float* v3  = (const float*)d_in[15];
    char*  wsb = (char*)d_ws;
    float* out = (float*)d_out;

    f16*   ptsT  = (f16*)  (wsb + OB_PTST);
    f16*   tc    = (f16*)  (wsb + OB_TC);
    float* Dinv  = (float*)(wsb + OB_D);
    f16*   xT    = (f16*)  (wsb + OB_XT);
    float* tp    = (float*)(wsb + T_TP);
    float* tr    = (float*)(wsb + T_TR);
    int*   inds  = (int*)  (wsb + T_INDS);
    f16*   fusek = (f16*)  (wsb + T_FUSEK);
    float* fuse  = (float*)(wsb + T_FUSE);

    // group size for LT/W region (deterministic from ws_size -> graph-safe)
    const size_t PER_B = 12845056ull + 6422528ull;   // LT + W per batch
    int GB = 1;
    for (int g = 8; g >= 1; --g) {
        size_t grp = (size_t)g * PER_B;
        size_t span = grp > 9011200ull ? grp : 9011200ull;
        if (ws_size >= OB_SH + span) { GB = g; break; }
    }
    float* LT = (float*)(wsb + OB_SH);
    f16*   W  = (f16*)  (wsb + OB_SH + (size_t)GB*12845056ull);

    k_xpose<<<dim3(98, 8, 8), 256, 0, stream>>>(x, xT);
    k_template<<<512, 256, 0, stream>>>(x, wrd, g1, b1, m1, v1, tp);
    k_argmax_gather<<<512, 256, 0, stream>>>(x, tp, tr);
    k_afftop<<<512, 256, 0, stream>>>(x, tr, inds);
    k_pointsT<<<dim3(8, 8, 8), 256, 0, stream>>>(x, inds, ptsT);
    k_fuse<<<256, 256, 0, stream>>>(x, wp, g2, b2, m2, v2, fusek, inds);
    k_maxk<<<2048, 256, 0, stream>>>(fusek, fuse);
    k_conv<<<256, 256, 0, stream>>>(wt, g3, b3, m3, v3, fuse, tc);

    for (int bs = 0; bs < B_; bs += GB) {
        int gb = (B_ - bs) < GB ? (B_ - bs) : GB;
        k_gemmL<<<dim3(49, 4, gb), 256, 0, stream>>>(xT, ptsT, LT, bs);
        k_softmaxW<<<dim3(1568, gb), 256, 0, stream>>>(LT, W, Dinv, bs);
        k_gemmP<<<dim3(49, 4, gb), 256, 0, stream>>>(tc, W, Dinv, x, out, bs);
    }
}

// Round 3
// 790.513 us; speedup vs baseline: 2.1353x; 1.2994x over previous
//
#include <hip/hip_runtime.h>

#define EPSB 1e-5f

// problem sizes
#define B_   8
#define C_   512
#define T_   8
#define HW_  784
#define S_   6272     // T*HW
#define R_   64
#define CQ_  128
#define K_   4
#define P_   512      // T*R

typedef _Float16 f16;
typedef __attribute__((ext_vector_type(8))) _Float16 f16x8;
typedef __attribute__((ext_vector_type(4))) _Float16 f16x4;
typedef __attribute__((ext_vector_type(4))) float    f32x4;

// ---- workspace byte offsets ----
#define OB_PTST  0ull                       // f16 [8][512][512]
#define OB_TC    4194304ull                 // f16 [8][512][512]
#define OB_D     8388608ull                 // f32 [8][6272]
#define OB_TRH   8589312ull                 // f16 [512][512]   (b*64+r rows)
#define OB_TRF   9113600ull                 // f32 [512][512]
#define OB_INDS  10162176ull                // int [8][4][8][64]
#define OB_WRH   10227712ull                // f16 [64][512]
#define OB_XT    10293248ull                // f16 [8][6272][512]  51,380,224
// transients (region reused over time; all dead before the gemm chunks)
#define T_TPA    61673472ull                // f32 [512][784]    1,605,632  (dead after targmax)
#define T_AFF    63279104ull                // f32 [512][6272]  12,845,056  (dead after topk)
#define T_FUSEK  61673472ull                // f16 [32][128][512] (written after tpa dead)
#define T_FUSE   65867776ull                // f32 [8][128][512]
#define CHB      61673472ull                // chunk region base (after conv everything above is dead)

__device__ __forceinline__ void gload16(const void* g, void* l) {
    __builtin_amdgcn_global_load_lds(
        (const __attribute__((address_space(1))) unsigned int*)g,
        (__attribute__((address_space(3))) unsigned int*)l, 16, 0, 0);
}

// ============================================================
// P0: convert w_reduce -> f16
__global__ __launch_bounds__(256) void k_prep(
    const float* __restrict__ wr, f16* __restrict__ wrh)
{
    int i = blockIdx.x*256 + threadIdx.x;   // 32768
    wrh[i] = (f16)wr[i];
}

// ============================================================
// K0: transpose+convert x[b][c][s] f32 -> xT[b][s][c] f16
__global__ __launch_bounds__(256) void k_xpose(
    const float* __restrict__ x, f16* __restrict__ xT)
{
    __shared__ float tile[64][65];
    int s0 = blockIdx.x*64, c0 = blockIdx.y*64, b = blockIdx.z;
    int tid = threadIdx.x;
    #pragma unroll
    for (int i = 0; i < 4; ++i) {
        int idx = tid + i*256;
        int cl = idx >> 4, s4 = (idx & 15)*4;
        f32x4 v = *(const f32x4*)&x[((size_t)(b*C_ + c0+cl))*S_ + s0 + s4];
        tile[cl][s4] = v.x; tile[cl][s4+1] = v.y;
        tile[cl][s4+2] = v.z; tile[cl][s4+3] = v.w;
    }
    __syncthreads();
    #pragma unroll
    for (int i = 0; i < 4; ++i) {
        int idx = tid + i*256;
        int sl = idx >> 4, c4 = (idx & 15)*4;
        f16x4 h;
        h[0] = (f16)tile[c4+0][sl]; h[1] = (f16)tile[c4+1][sl];
        h[2] = (f16)tile[c4+2][sl]; h[3] = (f16)tile[c4+3][sl];
        *(f16x4*)&xT[((size_t)(b*S_ + s0+sl))*C_ + c0 + c4] = h;
    }
}

// ============================================================
// K1: template dots via MFMA: tpa[b*64+r][s] = sum_c wrh[r][c]*xT[b][s][c]
// grid (7, 8): tile 128s x 64r, 4 waves (each 64s x 32r)
__global__ __launch_bounds__(256) void k_templ(
    const f16* __restrict__ xT, const f16* __restrict__ wrh,
    float* __restrict__ tpa)
{
    __shared__ __align__(16) f16 As[128*32];
    __shared__ __align__(16) f16 Bs[64*32];
    int b = blockIdx.y; int s0 = blockIdx.x*128;
    int tid = threadIdx.x;
    int lane = tid & 63, w = tid >> 6;
    int srow = w*16 + (lane >> 2);
    int scol = (lane & 3)*8;
    const f16* ga = xT  + ((size_t)b*S_ + s0 + srow)*C_ + scol;
    const f16* gb = wrh + (size_t)srow*C_ + scol;
    int mbase = (w & 1)*64, nbase = (w >> 1)*32;
    int fr = lane & 15, fk = (lane >> 4)*8, quad = lane >> 4;
    f32x4 acc[4][2] = {};
    for (int c0 = 0; c0 < C_; c0 += 32) {
        gload16(ga,         &As[w*512]);
        gload16(ga + 64*C_, &As[2048 + w*512]);
        gload16(gb,         &Bs[w*512]);
        ga += 32; gb += 32;
        __syncthreads();
        f16x8 af[4], bf[2];
        #pragma unroll
        for (int mt = 0; mt < 4; ++mt)
            af[mt] = *(const f16x8*)&As[(mbase + mt*16 + fr)*32 + fk];
        #pragma unroll
        for (int nt = 0; nt < 2; ++nt)
            bf[nt] = *(const f16x8*)&Bs[(nbase + nt*16 + fr)*32 + fk];
        #pragma unroll
        for (int mt = 0; mt < 4; ++mt)
            #pragma unroll
            for (int nt = 0; nt < 2; ++nt)
                acc[mt][nt] = __builtin_amdgcn_mfma_f32_16x16x32_f16(
                    af[mt], bf[nt], acc[mt][nt], 0, 0, 0);
        __syncthreads();
    }
    #pragma unroll
    for (int mt = 0; mt < 4; ++mt) {
        int sb = s0 + mbase + mt*16 + quad*4;
        #pragma unroll
        for (int nt = 0; nt < 2; ++nt) {
            int r = nbase + nt*16 + fr;
            #pragma unroll
            for (int i = 0; i < 4; ++i) {
                int ss = sb + i;
                if (ss < HW_)
                    tpa[((size_t)(b*R_ + r))*HW_ + ss] = acc[mt][nt][i];
            }
        }
    }
}

// ============================================================
// K2: per (b,r): approx argmax of tpa*sc, gap-guarded exact fp32 fallback,
//     then gather tr row (f32 + f16)
// grid 512 = b*64+r
__global__ __launch_bounds__(256) void k_targmax(
    const float* __restrict__ x, const float* __restrict__ wr_g,
    const float* __restrict__ g1, const float* __restrict__ v1,
    const float* __restrict__ tpa,
    float* __restrict__ trf, f16* __restrict__ trh)
{
    __shared__ float row[HW_];
    __shared__ float sval[256];
    __shared__ int   sidx[256];
    __shared__ float cval[4];
    __shared__ int   cidx[4];
    __shared__ float eval_[4];
    __shared__ int   bestind;
    int bid = blockIdx.x;
    int b = bid >> 6, r = bid & 63;
    int tid = threadIdx.x;
    float sc = g1[r] * rsqrtf(v1[r] + EPSB);
    const float* tprow = tpa + (size_t)bid*HW_;
    for (int s = tid; s < HW_; s += 256) row[s] = tprow[s]*sc;
    __syncthreads();
    for (int pass = 0; pass < 4; ++pass) {
        float best = -INFINITY; int bi = 0;
        for (int s = tid; s < HW_; s += 256) {
            float v = row[s];
            if (v > best) { best = v; bi = s; }
        }
        sval[tid] = best; sidx[tid] = bi;
        __syncthreads();
        for (int off = 128; off > 0; off >>= 1) {
            if (tid < off) {
                float ov = sval[tid+off]; int oi = sidx[tid+off];
                if (ov > sval[tid] || (ov == sval[tid] && oi < sidx[tid])) {
                    sval[tid] = ov; sidx[tid] = oi;
                }
            }
            __syncthreads();
        }
        if (tid == 0) {
            cval[pass] = sval[0]; cidx[pass] = sidx[0];
            row[sidx[0]] = -INFINITY;
        }
        __syncthreads();
    }
    float thr = 0.05f * fabsf(sc);
    if (cval[0] - cval[1] >= thr) {
        if (tid == 0) bestind = cidx[0];
    } else {
        // exact fp32 recompute of the 4 candidates
        int w = tid >> 6, lane = tid & 63;
        int cand = cidx[w];
        float sum = 0.f;
        #pragma unroll
        for (int i = 0; i < 8; ++i) {
            int c = lane + i*64;
            sum += wr_g[r*C_ + c] * x[((size_t)(b*C_ + c))*S_ + cand];
        }
        #pragma unroll
        for (int off = 32; off > 0; off >>= 1) sum += __shfl_xor(sum, off);
        if (lane == 0) eval_[w] = sum*sc;
        __syncthreads();
        if (tid == 0) {
            float bv = eval_[0]; int bi2 = cidx[0];
            for (int j = 1; j < 4; ++j) {
                float v = eval_[j]; int ii = cidx[j];
                if (v > bv || (v == bv && ii < bi2)) { bv = v; bi2 = ii; }
            }
            bestind = bi2;
        }
    }
    __syncthreads();
    int ind = bestind;
    for (int c = tid; c < C_; c += 256) {
        float v = x[((size_t)(b*C_ + c))*S_ + ind];
        trf[(size_t)bid*C_ + c] = v;
        trh[(size_t)bid*C_ + c] = (f16)v;
    }
}

// ============================================================
// K3: affinity via MFMA: aff[b*64+r][s] = sum_c trh[b*64+r][c]*xT[b][s][c]
// grid (49, 8): tile 128s x 64r
__global__ __launch_bounds__(256) void k_affin(
    const f16* __restrict__ xT, const f16* __restrict__ trh,
    float* __restrict__ aff)
{
    __shared__ __align__(16) f16 As[128*32];
    __shared__ __align__(16) f16 Bs[64*32];
    int b = blockIdx.y; int s0 = blockIdx.x*128;
    int tid = threadIdx.x;
    int lane = tid & 63, w = tid >> 6;
    int srow = w*16 + (lane >> 2);
    int scol = (lane & 3)*8;
    const f16* ga = xT  + ((size_t)b*S_ + s0 + srow)*C_ + scol;
    const f16* gb = trh + ((size_t)(b*R_) + srow)*C_ + scol;
    int mbase = (w & 1)*64, nbase = (w >> 1)*32;
    int fr = lane & 15, fk = (lane >> 4)*8, quad = lane >> 4;
    f32x4 acc[4][2] = {};
    for (int c0 = 0; c0 < C_; c0 += 32) {
        gload16(ga,         &As[w*512]);
        gload16(ga + 64*C_, &As[2048 + w*512]);
        gload16(gb,         &Bs[w*512]);
        ga += 32; gb += 32;
        __syncthreads();
        f16x8 af[4], bf[2];
        #pragma unroll
        for (int mt = 0; mt < 4; ++mt)
            af[mt] = *(const f16x8*)&As[(mbase + mt*16 + fr)*32 + fk];
        #pragma unroll
        for (int nt = 0; nt < 2; ++nt)
            bf[nt] = *(const f16x8*)&Bs[(nbase + nt*16 + fr)*32 + fk];
        #pragma unroll
        for (int mt = 0; mt < 4; ++mt)
            #pragma unroll
            for (int nt = 0; nt < 2; ++nt)
                acc[mt][nt] = __builtin_amdgcn_mfma_f32_16x16x32_f16(
                    af[mt], bf[nt], acc[mt][nt], 0, 0, 0);
        __syncthreads();
    }
    #pragma unroll
    for (int mt = 0; mt < 4; ++mt) {
        int sb = s0 + mbase + mt*16 + quad*4;
        #pragma unroll
        for (int nt = 0; nt < 2; ++nt) {
            int r = nbase + nt*16 + fr;
            size_t base = ((size_t)(b*R_ + r))*S_ + sb;
            #pragma unroll
            for (int i = 0; i < 4; ++i)
                aff[base + i] = acc[mt][nt][i];
        }
    }
}

// ============================================================
// K4: per (b,t,r): approx top-8 of aff row, gap-guarded exact fp32 fallback,
//     write top-4 indices
// grid (64 r, 8 t, 8 b)
__global__ __launch_bounds__(256) void k_topk(
    const float* __restrict__ x, const float* __restrict__ trf,
    const float* __restrict__ aff, int* __restrict__ inds)
{
    __shared__ float row[HW_];
    __shared__ float sval[256];
    __shared__ int   sidx[256];
    __shared__ float cval[8];
    __shared__ int   cidx[8];
    __shared__ float eval_[8];
    int r = blockIdx.x, t = blockIdx.y, b = blockIdx.z;
    int tid = threadIdx.x;
    const float* arow = aff + ((size_t)(b*R_ + r))*S_ + t*HW_;
    for (int s = tid; s < HW_; s += 256) row[s] = arow[s];
    __syncthreads();
    for (int pass = 0; pass < 8; ++pass) {
        float best = -INFINITY; int bi = 0;
        for (int s = tid; s < HW_; s += 256) {
            float v = row[s];
            if (v > best) { best = v; bi = s; }
        }
        sval[tid] = best; sidx[tid] = bi;
        __syncthreads();
        for (int off = 128; off > 0; off >>= 1) {
            if (tid < off) {
                float ov = sval[tid+off]; int oi = sidx[tid+off];
                if (ov > sval[tid] || (ov == sval[tid] && oi < sidx[tid])) {
                    sval[tid] = ov; sidx[tid] = oi;
                }
            }
            __syncthreads();
        }
        if (tid == 0) {
            cval[pass] = sval[0]; cidx[pass] = sidx[0];
            row[sidx[0]] = -INFINITY;
        }
        __syncthreads();
    }
    if (cval[3] - cval[4] >= 0.35f) {
        if (tid < K_)
            inds[((b*K_ + tid)*T_ + t)*R_ + r] = cidx[tid];
    } else {
        // exact fp32 recompute of the 8 candidates
        int w = tid >> 6, lane = tid & 63;
        #pragma unroll
        for (int half = 0; half < 2; ++half) {
            int j = w + half*4;
            int cand = cidx[j];
            float sum = 0.f;
            #pragma unroll
            for (int i = 0; i < 8; ++i) {
                int c = lane + i*64;
                sum += trf[((size_t)(b*R_ + r))*C_ + c]
                     * x[((size_t)(b*C_ + c))*S_ + t*HW_ + cand];
            }
            #pragma unroll
            for (int off = 32; off > 0; off >>= 1) sum += __shfl_xor(sum, off);
            if (lane == 0) eval_[j] = sum;
        }
        __syncthreads();
        if (tid == 0) {
            unsigned used = 0;
            for (int k = 0; k < K_; ++k) {
                float bv = -INFINITY; int bj = -1;
                for (int j = 0; j < 8; ++j) {
                    if (used & (1u << j)) continue;
                    float v = eval_[j]; int ii = cidx[j];
                    if (bj < 0 || v > bv || (v == bv && ii < cidx[bj])) {
                        bv = v; bj = j;
                    }
                }
                used |= 1u << bj;
                inds[((b*K_ + k)*T_ + t)*R_ + r] = cidx[bj];
            }
        }
    }
}

// ============================================================
// K5: ptsT[b][p][c] f16 = mean_k x[b,c,t,ind],  p=t*64+r
__global__ __launch_bounds__(256) void k_pointsT(
    const float* __restrict__ x, const int* __restrict__ inds,
    f16* __restrict__ ptsT)
{
    __shared__ float tile[64][65];
    __shared__ int   indl[4][64];
    int c0 = blockIdx.x*64, t = blockIdx.y, b = blockIdx.z;
    int tid = threadIdx.x;
    {
        int k = tid >> 6, r = tid & 63;
        indl[k][r] = inds[((b*K_ + k)*T_ + t)*R_ + r];
    }
    __syncthreads();
    #pragma unroll
    for (int i = 0; i < 16; ++i) {
        int idx = tid + i*256;
        int cl = idx >> 6, r = idx & 63;
        const float* base = x + (size_t)(b*C_ + c0 + cl)*S_ + t*HW_;
        float v = base[indl[0][r]] + base[indl[1][r]] + base[indl[2][r]] + base[indl[3][r]];
        tile[cl][r] = 0.25f*v;
    }
    __syncthreads();
    #pragma unroll
    for (int i = 0; i < 16; ++i) {
        int idx = tid + i*256;
        int rl = idx >> 6, cl = idx & 63;
        ptsT[((size_t)b*P_ + t*64 + rl)*C_ + c0 + cl] = (f16)tile[cl][rl];
    }
}

// ============================================================
// K6: fuse_k (bn2 proj of gathered traj + coords), out f16
__global__ __launch_bounds__(256) void k_fuse(
    const float* __restrict__ x, const float* __restrict__ wp,
    const float* __restrict__ g2, const float* __restrict__ b2,
    const float* __restrict__ m2, const float* __restrict__ v2,
    f16* __restrict__ fusek, const int* __restrict__ inds)
{
    __shared__ float wps[64][132];
    __shared__ float tile[64][64];
    __shared__ int   indr[64];
    __shared__ float rowv[64], colv[64];
    int bid = blockIdx.x;
    int t = bid & 7, bk = bid >> 3;
    int b = bk >> 2;
    int tid = threadIdx.x;
    if (tid < 64) {
        int id = inds[bk*T_*R_ + t*R_ + tid];
        indr[tid] = id;
        rowv[tid] = (float)(id / 28) * (1.0f/28.0f);
        colv[tid] = (float)(id % 28) * (1.0f/28.0f);
    }
    __syncthreads();
    int qg = tid >> 4, rg = tid & 15;
    float acc[8][4] = {};
    for (int c0 = 0; c0 < C_; c0 += 64) {
        #pragma unroll
        for (int i = 0; i < 32; ++i) {
            int li = tid + i*256;
            int q = li >> 6, cl = li & 63;
            wps[cl][q] = wp[q*514 + c0 + cl];
        }
        #pragma unroll
        for (int i = 0; i < 16; ++i) {
            int li = tid + i*256;
            int cl = li >> 6, r = li & 63;
            tile[cl][r] = x[(size_t)(b*C_ + c0 + cl)*S_ + t*HW_ + indr[r]];
        }
        __syncthreads();
        #pragma unroll 4
        for (int cl = 0; cl < 64; ++cl) {
            float tv[4], wv[8];
            float4 t0 = *(const float4*)&tile[cl][rg*4];
            tv[0]=t0.x; tv[1]=t0.y; tv[2]=t0.z; tv[3]=t0.w;
            float4 w0 = *(const float4*)&wps[cl][qg*8];
            float4 w1 = *(const float4*)&wps[cl][qg*8+4];
            wv[0]=w0.x; wv[1]=w0.y; wv[2]=w0.z; wv[3]=w0.w;
            wv[4]=w1.x; wv[5]=w1.y; wv[6]=w1.z; wv[7]=w1.w;
            #pragma unroll
            for (int jq = 0; jq < 8; ++jq)
                #pragma unroll
                for (int jr = 0; jr < 4; ++jr)
                    acc[jq][jr] += wv[jq]*tv[jr];
        }
        __syncthreads();
    }
    #pragma unroll
    for (int jq = 0; jq < 8; ++jq) {
        int q = qg*8 + jq;
        float wrow = wp[q*514 + 512], wcol = wp[q*514 + 513];
        float sc = g2[q] * rsqrtf(v2[q] + EPSB);
        float sh = b2[q] - m2[q]*sc;
        #pragma unroll
        for (int jr = 0; jr < 4; ++jr) {
            int r = rg*4 + jr;
            float v = acc[jq][jr] + wrow*rowv[r] + wcol*colv[r];
            fusek[(size_t)(bk*CQ_ + q)*P_ + t*R_ + r] = (f16)(v*sc + sh);
        }
    }
}

// ============================================================
// K7: fuse[b,q,p] = max_k fuse_k
__global__ __launch_bounds__(256) void k_maxk(
    const f16* __restrict__ fusek, float* __restrict__ fuse)
{
    int idx = blockIdx.x*256 + threadIdx.x;
    int b = idx >> 16;
    int qp = idx & 65535;
    const f16* base = fusek + (size_t)(b*4)*CQ_*P_ + qp;
    float m = (float)base[0];
    #pragma unroll
    for (int k = 1; k < K_; ++k) m = fmaxf(m, (float)base[(size_t)k*CQ_*P_]);
    fuse[(size_t)idx] = m;
}

// ============================================================
// K8: temporal conv + bn3 + relu -> tc f16 [b][c][p]
__global__ __launch_bounds__(256) void k_conv(
    const float* __restrict__ wt,
    const float* __restrict__ g3, const float* __restrict__ b3,
    const float* __restrict__ m3, const float* __restrict__ v3,
    const float* __restrict__ fuse, f16* __restrict__ tc)
{
    __shared__ float fs[64][64];
    __shared__ float wts[128][65];
    int bid = blockIdx.x;
    int t = bid & 7, cb = (bid >> 3) & 3, b = bid >> 5;
    int tid = threadIdx.x;
    int cog = tid >> 4, rg = tid & 15;
    float acc[8][4] = {};
    for (int dt = 0; dt < 3; ++dt) {
        int tt = t + dt - 1;
        if (tt < 0 || tt >= T_) continue;
        for (int cih = 0; cih < 2; ++cih) {
            __syncthreads();
            #pragma unroll
            for (int i = 0; i < 16; ++i) {
                int li = tid + i*256;
                int ci = li >> 6, r = li & 63;
                fs[ci][r] = fuse[(size_t)(b*CQ_ + cih*64 + ci)*P_ + tt*R_ + r];
            }
            #pragma unroll
            for (int i = 0; i < 32; ++i) {
                int li = tid + i*256;
                int col = li >> 6, ci = li & 63;
                wts[col][ci] = wt[(size_t)((cb*128 + col)*CQ_ + cih*64 + ci)*3 + dt];
            }
            __syncthreads();
            #pragma unroll 4
            for (int ci = 0; ci < 64; ++ci) {
                float fv[4];
                float4 f0 = *(const float4*)&fs[ci][rg*4];
                fv[0]=f0.x; fv[1]=f0.y; fv[2]=f0.z; fv[3]=f0.w;
                #pragma unroll
                for (int jq = 0; jq < 8; ++jq) {
                    float wv = wts[cog + 16*jq][ci];
                    #pragma unroll
                    for (int jr = 0; jr < 4; ++jr) acc[jq][jr] += wv*fv[jr];
                }
            }
        }
    }
    #pragma unroll
    for (int jq = 0; jq < 8; ++jq) {
        int co = cb*128 + cog + 16*jq;
        float sc = g3[co] * rsqrtf(v3[co] + EPSB);
        float sh = b3[co] - m3[co]*sc;
        f16x4 h;
        #pragma unroll
        for (int jr = 0; jr < 4; ++jr)
            h[jr] = (f16)fmaxf(acc[jq][jr]*sc + sh, 0.f);
        *(f16x4*)&tc[((size_t)(b*C_ + co))*P_ + t*R_ + rg*4] = h;
    }
}

// ============================================================
// K9: LT chunk GEMM: LT[(b*NCHb+lt)*128+row][p] = sum_c xT[s][c]*ptsT[p][c]
// grid (cnt, 4, 8)
__global__ __launch_bounds__(256) void k_gemmL(
    const f16* __restrict__ xT, const f16* __restrict__ ptsT,
    float* __restrict__ LT, int st, int NCHb)
{
    __shared__ __align__(16) f16 As[128*32];
    __shared__ __align__(16) f16 Bs[128*32];
    int lt = blockIdx.x; int b = blockIdx.z;
    int s0 = (st + lt)*128, p0 = blockIdx.y*128;
    int tid = threadIdx.x;
    int lane = tid & 63, w = tid >> 6;
    int srow = w*16 + (lane >> 2);
    int scol = (lane & 3)*8;
    const f16* ga = xT   + ((size_t)b*S_ + s0 + srow)*C_ + scol;
    const f16* gb = ptsT + ((size_t)b*P_ + p0 + srow)*C_ + scol;
    float* Lg = LT + ((size_t)(b*NCHb + lt))*128*P_;
    int mrow = (w & 1)*64, nrow = (w >> 1)*64;
    int fr = lane & 15, fk = (lane >> 4)*8, quad = lane >> 4;
    f32x4 acc[4][4] = {};
    for (int c0 = 0; c0 < C_; c0 += 32) {
        gload16(ga,           &As[w*512]);
        gload16(ga + 64*C_,   &As[2048 + w*512]);
        gload16(gb,           &Bs[w*512]);
        gload16(gb + 64*C_,   &Bs[2048 + w*512]);
        ga += 32; gb += 32;
        __syncthreads();
        f16x8 af[4], bf[4];
        #pragma unroll
        for (int mt = 0; mt < 4; ++mt)
            af[mt] = *(const f16x8*)&As[(mrow + mt*16 + fr)*32 + fk];
        #pragma unroll
        for (int nt = 0; nt < 4; ++nt)
            bf[nt] = *(const f16x8*)&Bs[(nrow + nt*16 + fr)*32 + fk];
        #pragma unroll
        for (int mt = 0; mt < 4; ++mt)
            #pragma unroll
            for (int nt = 0; nt < 4; ++nt)
                acc[mt][nt] = __builtin_amdgcn_mfma_f32_16x16x32_f16(
                    af[mt], bf[nt], acc[mt][nt], 0, 0, 0);
        __syncthreads();
    }
    #pragma unroll
    for (int mt = 0; mt < 4; ++mt) {
        int lrow = mrow + mt*16 + quad*4;
        #pragma unroll
        for (int nt = 0; nt < 4; ++nt) {
            int p = p0 + nrow + nt*16 + fr;
            #pragma unroll
            for (int i = 0; i < 4; ++i)
                Lg[(size_t)(lrow + i)*P_ + p] = acc[mt][nt][i];
        }
    }
}

// ============================================================
// K10: row softmax over p for chunk rows: W f16 = exp(L-m), Dinv = 1/sum
// grid (cnt*32, 8); one wave per row
__global__ __launch_bounds__(256) void k_softmaxW(
    const float* __restrict__ LT, f16* __restrict__ W,
    float* __restrict__ Dinv, int st, int NCHb)
{
    int b = blockIdx.y;
    int tid = threadIdx.x, w = tid >> 6, lane = tid & 63;
    int gr = blockIdx.x*4 + w;              // 0 .. cnt*128
    int lt = gr >> 7, lrow = gr & 127;
    size_t base = ((size_t)(b*NCHb + lt)*128 + lrow)*P_;
    const float* row = LT + base + lane*8;
    f32x4 v0 = *(const f32x4*)row;
    f32x4 v1 = *(const f32x4*)(row + 4);
    float m = fmaxf(fmaxf(fmaxf(v0.x, v0.y), fmaxf(v0.z, v0.w)),
                    fmaxf(fmaxf(v1.x, v1.y), fmaxf(v1.z, v1.w)));
    #pragma unroll
    for (int off = 1; off < 64; off <<= 1) m = fmaxf(m, __shfl_xor(m, off));
    float e[8];
    e[0] = __expf(v0.x - m); e[1] = __expf(v0.y - m);
    e[2] = __expf(v0.z - m); e[3] = __expf(v0.w - m);
    e[4] = __expf(v1.x - m); e[5] = __expf(v1.y - m);
    e[6] = __expf(v1.z - m); e[7] = __expf(v1.w - m);
    float sum = ((e[0]+e[1])+(e[2]+e[3])) + ((e[4]+e[5])+(e[6]+e[7]));
    #pragma unroll
    for (int off = 1; off < 64; off <<= 1) sum += __shfl_xor(sum, off);
    f16x8 h;
    #pragma unroll
    for (int j = 0; j < 8; ++j) h[j] = (f16)e[j];
    *(f16x8*)&W[base + lane*8] = h;
    if (lane == 0) Dinv[(size_t)b*S_ + (st + lt)*128 + lrow] = 1.0f/sum;
}

// ============================================================
// K11: out[b][c][s] = x + Dinv[s] * sum_p tc[b][c][p] * W[row(s)][p]
// grid (cnt, 4, 8)
__global__ __launch_bounds__(256) void k_gemmP(
    const f16* __restrict__ tc, const f16* __restrict__ W,
    const float* __restrict__ Dinv, const float* __restrict__ x,
    float* __restrict__ out, int st, int NCHb)
{
    __shared__ __align__(16) f16 As[128*32];
    __shared__ __align__(16) f16 Bs[128*32];
    int lt = blockIdx.x; int b = blockIdx.z;
    int s0 = (st + lt)*128, c0t = blockIdx.y*128;
    int tid = threadIdx.x;
    int lane = tid & 63, w = tid >> 6;
    int srow = w*16 + (lane >> 2);
    int scol = (lane & 3)*8;
    const f16* ga = tc + ((size_t)(b*C_) + c0t + srow)*P_ + scol;
    const f16* gb = W  + ((size_t)(b*NCHb + lt)*128 + srow)*P_ + scol;
    int mrow = (w & 1)*64, nrow = (w >> 1)*64;
    int fr = lane & 15, fk = (lane >> 4)*8, quad = lane >> 4;
    f32x4 acc[4][4] = {};
    for (int p0 = 0; p0 < P_; p0 += 32) {
        gload16(ga,           &As[w*512]);
        gload16(ga + 64*P_,   &As[2048 + w*512]);
        gload16(gb,           &Bs[w*512]);
        gload16(gb + 64*P_,   &Bs[2048 + w*512]);
        ga += 32; gb += 32;
        __syncthreads();
        f16x8 af[4], bf[4];
        #pragma unroll
        for (int mt = 0; mt < 4; ++mt)
            af[mt] = *(const f16x8*)&As[(mrow + mt*16 + fr)*32 + fk];
        #pragma unroll
        for (int nt = 0; nt < 4; ++nt)
            bf[nt] = *(const f16x8*)&Bs[(nrow + nt*16 + fr)*32 + fk];
        #pragma unroll
        for (int mt = 0; mt < 4; ++mt)
            #pragma unroll
            for (int nt = 0; nt < 4; ++nt)
                acc[mt][nt] = __builtin_amdgcn_mfma_f32_16x16x32_f16(
                    af[mt], bf[nt], acc[mt][nt], 0, 0, 0);
        __syncthreads();
    }
    #pragma unroll
    for (int nt = 0; nt < 4; ++nt) {
        int s = s0 + nrow + nt*16 + fr;
        float dv = Dinv[(size_t)b*S_ + s];
        #pragma unroll
        for (int mt = 0; mt < 4; ++mt) {
            int c = c0t + mrow + mt*16 + quad*4;
            #pragma unroll
            for (int i = 0; i < 4; ++i) {
                size_t o = ((size_t)(b*C_ + c + i))*S_ + s;
                out[o] = x[o] + acc[mt][nt][i]*dv;
            }
        }
    }
}

// ============================================================
extern "C" void kernel_launch(void* const* d_in, const int* in_sizes, int n_in,
                              void* d_out, int out_size, void* d_ws, size_t ws_size,
                              hipStream_t stream) {
    const float* x   = (const float*)d_in[0];
    const float* wrd = (const float*)d_in[1];
    const float* g1  = (const float*)d_in[2];
    const float* v1  = (const float*)d_in[5];
    const float* wp  = (const float*)d_in[6];
    const float* g2  = (const float*)d_in[7];
    const float* b2  = (const float*)d_in[8];
    const float* m2  = (const float*)d_in[9];
    const float* v2  = (const float*)d_in[10];
    const float* wt  = (const float*)d_in[11];
    const float* g3  = (const float*)d_in[12];
    const float* b3  = (const float*)d_in[13];
    const float* m3  = (const float*)d_in[14];
    const float* v3  = (const float*)d_in[15];
    char*  wsb = (char*)d_ws;
    float* out = (float*)d_out;

    f16*   ptsT  = (f16*)  (wsb + OB_PTST);
    f16*   tc    = (f16*)  (wsb + OB_TC);
    float* Dinv  = (float*)(wsb + OB_D);
    f16*   trh   = (f16*)  (wsb + OB_TRH);
    float* trf   = (float*)(wsb + OB_TRF);
    int*   inds  = (int*)  (wsb + OB_INDS);
    f16*   wrh   = (f16*)  (wsb + OB_WRH);
    f16*   xT    = (f16*)  (wsb + OB_XT);
    float* tpa   = (float*)(wsb + T_TPA);
    float* aff   = (float*)(wsb + T_AFF);
    f16*   fusek = (f16*)  (wsb + T_FUSEK);
    float* fuse  = (float*)(wsb + T_FUSE);

    // s-tile chunking (deterministic from ws_size -> graph-safe)
    const size_t PER_TILE = 3145728ull;   // LT f32 + W f16, all 8 batches
    size_t avail = ws_size > CHB ? ws_size - CHB : 0;
    int NCH = (int)(avail / PER_TILE);
    if (NCH < 1) NCH = 1;
    if (NCH > 49) NCH = 49;
    int nchunks = (49 + NCH - 1)/NCH;
    int NCHb = (49 + nchunks - 1)/nchunks;
    float* LT = (float*)(wsb + CHB);
    f16*   W  = (f16*)  (wsb + CHB + (size_t)NCHb*8ull*128ull*P_*4ull);

    k_prep<<<128, 256, 0, stream>>>(wrd, wrh);
    k_xpose<<<dim3(98, 8, 8), 256, 0, stream>>>(x, xT);
    k_templ<<<dim3(7, 8), 256, 0, stream>>>(xT, wrh, tpa);
    k_targmax<<<512, 256, 0, stream>>>(x, wrd, g1, v1, tpa, trf, trh);
    k_affin<<<dim3(49, 8), 256, 0, stream>>>(xT, trh, aff);
    k_topk<<<dim3(R_, T_, B_), 256, 0, stream>>>(x, trf, aff, inds);
    k_pointsT<<<dim3(8, 8, 8), 256, 0, stream>>>(x, inds, ptsT);
    k_fuse<<<256, 256, 0, stream>>>(x, wp, g2, b2, m2, v2, fusek, inds);
    k_maxk<<<2048, 256, 0, stream>>>(fusek, fuse);
    k_conv<<<256, 256, 0, stream>>>(wt, g3, b3, m3, v3, fuse, tc);

    for (int st = 0; st < 49; st += NCHb) {
        int cnt = (49 - st) < NCHb ? (49 - st) : NCHb;
        k_gemmL<<<dim3(cnt, 4, 8), 256, 0, stream>>>(xT, ptsT, LT, st, NCHb);
        k_softmaxW<<<dim3(cnt*32, 8), 256, 0, stream>>>(LT, W, Dinv, st, NCHb);
        k_gemmP<<<dim3(cnt, 4, 8), 256, 0, stream>>>(tc, W, Dinv, x, out, st, NCHb);
    }
}